// Round 6
// baseline (6719.883 us; speedup 1.0000x reference)
//
#include <hip/hip_runtime.h>
#include <math.h>

#define T_STEPS 64
#define BB 64
#define LL 2048
#define EE 128
#define HH 256
#define NCHUNK 32
#define LCHUNK (LL / NCHUNK) /* 64 */

__device__ __forceinline__ float fexp(float x) {
    return __builtin_amdgcn_exp2f(x * 1.44269504088896340736f);
}
__device__ __forceinline__ float fsig(float x) {
    return __builtin_amdgcn_rcpf(1.f + __builtin_amdgcn_exp2f(-1.44269504088896340736f * x));
}
__device__ __forceinline__ float ftanh(float x) {
    float xc = fminf(fmaxf(x, -20.f), 20.f);
    float p = __builtin_amdgcn_exp2f(2.885390081777926814f * xc); // e^{2x}
    return (p - 1.f) * __builtin_amdgcn_rcpf(p + 1.f);
}
__device__ __forceinline__ unsigned int bfr(float x) {
    unsigned int u = __float_as_uint(x);
    return (u + 0x7FFFu + ((u >> 16) & 1u)) >> 16;
}
__device__ __forceinline__ void bf8x(const uint4 q, float* f) {
    f[0] = __uint_as_float(q.x << 16); f[1] = __uint_as_float(q.x & 0xFFFF0000u);
    f[2] = __uint_as_float(q.y << 16); f[3] = __uint_as_float(q.y & 0xFFFF0000u);
    f[4] = __uint_as_float(q.z << 16); f[5] = __uint_as_float(q.z & 0xFFFF0000u);
    f[6] = __uint_as_float(q.w << 16); f[7] = __uint_as_float(q.w & 0xFFFF0000u);
}
__device__ __forceinline__ void load8(const float* p, float* d) {
    float4 a = *(const float4*)p, b = *(const float4*)(p + 4);
    d[0]=a.x; d[1]=a.y; d[2]=a.z; d[3]=a.w; d[4]=b.x; d[5]=b.y; d[6]=b.z; d[7]=b.w;
}

// ---------------------------------------------------------------------------
// K0: one-time fp32 -> bf16 conversion of enc (RNE).
// ---------------------------------------------------------------------------
__global__ __launch_bounds__(256) void conv_kernel(
    const float4* __restrict__ enc, uint4* __restrict__ encb)
{
    const int n = BB * LL * HH / 8;
    for (int i = blockIdx.x * 256 + threadIdx.x; i < n; i += gridDim.x * 256) {
        const float4 a = enc[2 * i], c = enc[2 * i + 1];
        uint4 o;
        o.x = bfr(a.x) | (bfr(a.y) << 16);
        o.y = bfr(a.z) | (bfr(a.w) << 16);
        o.z = bfr(c.x) | (bfr(c.y) << 16);
        o.w = bfr(c.z) | (bfr(c.w) << 16);
        encb[i] = o;
    }
}

// ---------------------------------------------------------------------------
// K1: attention pass for step t (bf16 enc), fused with step-(t-1) epilogue
// (attns[t-1] write + cov rmw; block owns its (b,l-slice) -> race-free).
// FULL prefetch: all 8 enc uint4 + all per-row scalars issued before compute
// (attacks L3 latency: 8+ outstanding loads/lane instead of 2).
// Grid: NCHUNK*BB = 2048 blocks, 256 threads.
// ---------------------------------------------------------------------------
__global__ __launch_bounds__(256) void attn_kernel(
    const uint4* __restrict__ encb,  // (B*L, 32) uint4 (=256 bf16 per row)
    const float* __restrict__ mask,
    float* __restrict__ cov,
    const float* __restrict__ df,
    const float* __restrict__ v,
    const float* __restrict__ wc,
    float* __restrict__ e_ws,        // (2,B,L)
    float* __restrict__ attns,
    const float* __restrict__ m_ws,
    const float* __restrict__ is_ws,
    float* __restrict__ mp, float* __restrict__ sp, float* __restrict__ ctxp,
    int t)
{
    const int prev_t = t - 1;
    const int g = blockIdx.x;
    const int b = g & (BB - 1);
    const int chunk = g >> 6;
    const int tid = threadIdx.x;
    const int wave = tid >> 6;
    const int lane = tid & 63;
    const int hc = lane & 15;
    const int lsub = lane >> 4;
    const int l0 = chunk * LCHUNK + wave * (LCHUNK / 4);

    const float* e_prev = e_ws + (size_t)(prev_t & 1) * BB * LL;
    float* e_cur = e_ws + (size_t)(t & 1) * BB * LL;

    // ---- issue ALL long-latency loads first ----
    uint4 eA[8];
    const uint4* ep0 = encb + (size_t)(b * LL + l0 + lsub) * 32 + hc;
    #pragma unroll
    for (int mi = 0; mi < 4; ++mi) {
        eA[2 * mi]     = ep0[mi * 128];
        eA[2 * mi + 1] = ep0[mi * 128 + 16];
    }
    float mskv[4], covv[4], epv[4];
    #pragma unroll
    for (int mi = 0; mi < 4; ++mi) {
        const int idx = b * LL + l0 + mi * 4 + lsub;
        mskv[mi] = mask[idx];
        covv[mi] = (prev_t >= 0) ? cov[idx] : 0.f;
        epv[mi]  = (prev_t >= 0) ? e_prev[idx] : 0.f;
    }
    float dfv[16], vv[16], wcv[16];
    #pragma unroll
    for (int k = 0; k < 2; ++k) {
        load8(df + b * HH + hc * 8 + 128 * k, dfv + 8 * k);
        load8(v + hc * 8 + 128 * k, vv + 8 * k);
        load8(wc + hc * 8 + 128 * k, wcv + 8 * k);
    }
    float Mprev = 0.f, iSprev = 0.f;
    if (prev_t >= 0) { Mprev = m_ws[b]; iSprev = is_ws[b]; }

    // ---- step-(t-1) epilogue: attn weight, coverage rmw ----
    float cvv[4];
    #pragma unroll
    for (int mi = 0; mi < 4; ++mi) {
        const int l = l0 + mi * 4 + lsub;
        const int idx = b * LL + l;
        if (prev_t >= 0) {
            const float a = fexp(epv[mi] - Mprev) * mskv[mi] * iSprev;
            cvv[mi] = covv[mi] + a;
            if (hc == 0) {
                cov[idx] = cvv[mi];
                attns[((size_t)prev_t * BB + b) * LL + l] = a;
            }
        } else {
            cvv[mi] = 0.f;
            if (hc == 0) cov[idx] = 0.f;
        }
    }

    float m = -INFINITY, s = 0.f;
    float cacc[16];
    #pragma unroll
    for (int j = 0; j < 16; ++j) cacc[j] = 0.f;

    #pragma unroll
    for (int mi = 0; mi < 4; ++mi) {
        float fe[16];
        bf8x(eA[2 * mi], fe); bf8x(eA[2 * mi + 1], fe + 8);
        float p = 0.f;
        #pragma unroll
        for (int j = 0; j < 16; ++j)
            p += vv[j] * ftanh(fe[j] + dfv[j] + cvv[mi] * wcv[j]);
        p += __shfl_xor(p, 1);
        p += __shfl_xor(p, 2);
        p += __shfl_xor(p, 4);
        p += __shfl_xor(p, 8);
        const int l = l0 + mi * 4 + lsub;
        if (hc == 0) e_cur[b * LL + l] = p;

        const float mn = fmaxf(m, p);
        const float sc = fexp(m - mn);
        const float w  = fexp(p - mn) * mskv[mi];
        s = s * sc + w;
        #pragma unroll
        for (int j = 0; j < 16; ++j) cacc[j] = cacc[j] * sc + w * fe[j];
        m = mn;
    }

    // cross-subgroup butterfly (xor 16, 32) with max-rescale
    #pragma unroll
    for (int off = 16; off <= 32; off <<= 1) {
        const float m2 = __shfl_xor(m, off);
        const float s2 = __shfl_xor(s, off);
        const float mn = fmaxf(m, m2);
        const float wa = fexp(m - mn), wb = fexp(m2 - mn);
        s = s * wa + s2 * wb;
        #pragma unroll
        for (int j = 0; j < 16; ++j) {
            const float c2 = __shfl_xor(cacc[j], off);
            cacc[j] = cacc[j] * wa + c2 * wb;
        }
        m = mn;
    }

    __shared__ float lm[4], lsum[4];
    __shared__ float lctx[4][HH];
    if (lsub == 0) {
        #pragma unroll
        for (int k = 0; k < 2; ++k)
            #pragma unroll
            for (int j = 0; j < 8; ++j)
                lctx[wave][hc * 8 + 128 * k + j] = cacc[k * 8 + j];
    }
    if (lane == 0) { lm[wave] = m; lsum[wave] = s; }
    __syncthreads();

    const float M = fmaxf(fmaxf(lm[0], lm[1]), fmaxf(lm[2], lm[3]));
    const float w0 = fexp(lm[0] - M), w1 = fexp(lm[1] - M),
                w2 = fexp(lm[2] - M), w3 = fexp(lm[3] - M);
    const int pidx = chunk * BB + b;
    ctxp[(size_t)pidx * HH + tid] =
        lctx[0][tid] * w0 + lctx[1][tid] * w1 + lctx[2][tid] * w2 + lctx[3][tid] * w3;
    if (tid == 0) {
        mp[pidx] = M;
        sp[pidx] = lsum[0] * w0 + lsum[1] * w1 + lsum[2] * w2 + lsum[3] * w3;
    }
}

// ---------------------------------------------------------------------------
// K2: fused recurrent core for step t: ctx combine (t-1) + x_t + LSTM z + c,h.
// Grid 128 blocks = (bg: 16 groups of 4 batches) x (us: 8 slices of 32 units).
// 256 threads. x is computed redundantly per unit-slice (cheap); z-slice is
// gate-structured: cols {g*256 + us*32 + uu}. All blocks write disjoint
// (b, unit) outputs -> race-free. t==T_STEPS: final ctx combine only.
// ---------------------------------------------------------------------------
__global__ __launch_bounds__(256) void recur_kernel(
    const float* __restrict__ dec_in,
    const float* __restrict__ mp, const float* __restrict__ sp,
    const float* __restrict__ ctxp,
    const float* __restrict__ init_c, const float* __restrict__ init_h,
    const float* __restrict__ Wx, const float* __restrict__ bx,
    const float* __restrict__ Wl, const float* __restrict__ bl,
    float* __restrict__ ctx_hist, float* __restrict__ x_hist,
    float* __restrict__ c_hist, float* __restrict__ h_hist,
    float* __restrict__ m_ws, float* __restrict__ is_ws, int t)
{
    const int bg = blockIdx.x >> 3;
    const int us = blockIdx.x & 7;
    const int tid = threadIdx.x;
    const int b0 = bg * 4;
    __shared__ float sctx[4][HH];
    __shared__ float sxh[4][EE + HH + 1];   // f = [x(128), h(256)], padded
    __shared__ float siv[4][EE];
    __shared__ float zs[4][128];

    const float* hsrc = (t == 0) ? init_h : h_hist + (size_t)(t - 1) * BB * HH;
    const float* csrc = (t == 0) ? init_c : c_hist + (size_t)(t - 1) * BB * HH;

    // phase 1: ctx combine (j = tid), h_prev staging, dec_in staging
    if (t > 0) {
        #pragma unroll
        for (int bi = 0; bi < 4; ++bi) {
            const int b = b0 + bi;
            float M = -INFINITY;
            #pragma unroll
            for (int k = 0; k < NCHUNK; ++k) M = fmaxf(M, mp[k * BB + b]);
            float S = 0.f, cs = 0.f;
            #pragma unroll
            for (int k = 0; k < NCHUNK; ++k) {
                const float w = fexp(mp[k * BB + b] - M);
                S += sp[k * BB + b] * w;
                cs += ctxp[(size_t)(k * BB + b) * HH + tid] * w;
            }
            const float invS = 1.f / S;
            const float cx = cs * invS;
            sctx[bi][tid] = cx;
            if (us == 0) {
                ctx_hist[((size_t)(t - 1) * BB + b) * HH + tid] = cx;
                if (tid == 0) { m_ws[b] = M; is_ws[b] = invS; }
            }
        }
    } else {
        #pragma unroll
        for (int bi = 0; bi < 4; ++bi) sctx[bi][tid] = 0.f;
    }

    if (t < T_STEPS) {
        for (int i = tid; i < 4 * HH; i += 256) {
            const int bi = i >> 8, k = i & 255;
            sxh[bi][EE + k] = hsrc[(b0 + bi) * HH + k];
        }
        for (int i = tid; i < 4 * EE; i += 256) {
            const int bi = i >> 7, k = i & 127;
            siv[bi][k] = dec_in[((size_t)t * BB + b0 + bi) * EE + k];
        }
    }
    __syncthreads();
    if (t >= T_STEPS) return;

    // phase 2: x = relu([inp, ctx] @ W_x + b_x); thread -> (j, bi & bi+2)
    {
        const int j = tid & 127, bh = tid >> 7;
        float a0 = bx[j], a1 = a0;
        const float* w = Wx + j;
        #pragma unroll 4
        for (int r = 0; r < EE + HH; ++r) {
            const float wv = w[(size_t)r * EE];
            const float f0 = (r < EE) ? siv[bh][r] : sctx[bh][r - EE];
            const float f1 = (r < EE) ? siv[bh + 2][r] : sctx[bh + 2][r - EE];
            a0 += f0 * wv; a1 += f1 * wv;
        }
        a0 = fmaxf(a0, 0.f); a1 = fmaxf(a1, 0.f);
        sxh[bh][j] = a0; sxh[bh + 2][j] = a1;
        if (us == 0) {
            x_hist[((size_t)t * BB + b0 + bh) * EE + j] = a0;
            x_hist[((size_t)t * BB + b0 + bh + 2) * EE + j] = a1;
        }
    }
    __syncthreads();

    // phase 3: z-slice; thread -> (c = g*32+uu, bi & bi+2)
    {
        const int c = tid & 127, bh = tid >> 7;
        const int gg = c >> 5, uu = c & 31;
        const int zcol = gg * 256 + us * 32 + uu;
        float z0 = bl[zcol], z1 = z0;
        const float* w = Wl + zcol;
        #pragma unroll 4
        for (int r = 0; r < EE + HH; ++r) {
            const float wv = w[(size_t)r * 1024];
            z0 += sxh[bh][r] * wv;
            z1 += sxh[bh + 2][r] * wv;
        }
        zs[bh][c] = z0; zs[bh + 2][c] = z1;
    }
    __syncthreads();

    // phase 4: c,h update for (4 b x 32 units)
    if (tid < 128) {
        const int bi = tid >> 5, uu = tid & 31;
        const int u = us * 32 + uu;
        const float zi = zs[bi][uu], zf = zs[bi][32 + uu],
                    zg = zs[bi][64 + uu], zo = zs[bi][96 + uu];
        const float cp = csrc[(b0 + bi) * HH + u];
        const float cn = fsig(zf) * cp + fsig(zi) * ftanh(zg);
        const float hn = fsig(zo) * ftanh(cn);
        c_hist[((size_t)t * BB + b0 + bi) * HH + u] = cn;
        h_hist[((size_t)t * BB + b0 + bi) * HH + u] = hn;
    }
}

// ---------------------------------------------------------------------------
// K3: dec_feat_t = tanh([c_t, h_t] @ W_s + b_s). Grid BB, 512 threads.
// ---------------------------------------------------------------------------
__global__ __launch_bounds__(512) void df_kernel(
    const float* __restrict__ c_hist, const float* __restrict__ h_hist,
    const float* __restrict__ Ws, const float* __restrict__ bs,
    float* __restrict__ df_ws, int t)
{
    const int b = blockIdx.x;
    const int tid = threadIdx.x;
    __shared__ float sf[512];
    __shared__ float rbuf[256];
    sf[tid] = (tid < 256) ? c_hist[((size_t)t * BB + b) * HH + tid]
                          : h_hist[((size_t)t * BB + b) * HH + tid - 256];
    __syncthreads();
    const int j = tid & 255, half = tid >> 8;
    float a = 0.f;
    const float* wcol = Ws + (size_t)(half * 256) * HH + j;
    const float* src = sf + half * 256;
    #pragma unroll 4
    for (int r = 0; r < 256; ++r) a += src[r] * wcol[(size_t)r * HH];
    if (half) rbuf[j] = a;
    __syncthreads();
    if (!half) df_ws[b * HH + j] = ftanh(a + rbuf[j] + bs[j]);
}

// ---------------------------------------------------------------------------
// K4: epilogue: attns[T-1], final cov, c/h outputs. Grid BB, 256 threads.
// ---------------------------------------------------------------------------
__global__ __launch_bounds__(256) void epi_kernel(
    const float* __restrict__ e_ws, const float* __restrict__ mask,
    const float* __restrict__ m_ws, const float* __restrict__ is_ws,
    const float* __restrict__ c_hist, const float* __restrict__ h_hist,
    float* __restrict__ attns, float* __restrict__ cov,
    float* __restrict__ c_out, float* __restrict__ h_out)
{
    const int b = blockIdx.x;
    const int j = threadIdx.x;
    const float Mp = m_ws[b], iS = is_ws[b];
    const float* e_last = e_ws + (size_t)((T_STEPS - 1) & 1) * BB * LL;
    for (int i = 0; i < LL / 256; ++i) {
        const int l = i * 256 + j;
        const int idx = b * LL + l;
        const float a = fexp(e_last[idx] - Mp) * mask[idx] * iS;
        attns[((size_t)(T_STEPS - 1) * BB + b) * LL + l] = a;
        cov[idx] += a;
    }
    c_out[b * HH + j] = c_hist[((size_t)(T_STEPS - 1) * BB + b) * HH + j];
    h_out[b * HH + j] = h_hist[((size_t)(T_STEPS - 1) * BB + b) * HH + j];
}

// ---------------------------------------------------------------------------
// K5: batched outs + pgens over all (t,b). Grid 256 blocks = (t, b-quarter).
// ---------------------------------------------------------------------------
__global__ __launch_bounds__(256) void out_kernel(
    const float* __restrict__ h_hist, const float* __restrict__ ctx_hist,
    const float* __restrict__ c_hist, const float* __restrict__ x_hist,
    const float* __restrict__ Wo, const float* __restrict__ bo,
    const float* __restrict__ Wp, const float* __restrict__ bp,
    float* __restrict__ outs, float* __restrict__ pgens)
{
    const int t = blockIdx.x >> 2;
    const int bq = blockIdx.x & 3;
    const int tid = threadIdx.x;
    __shared__ float hs[16 * 256], cts[16 * 256], cs2[16 * 256], xs[16 * 128];

    for (int i = tid; i < 16 * 256; i += 256) {
        const int bl = i >> 8, j = i & 255;
        const size_t row = ((size_t)t * BB + bq * 16 + bl) * HH;
        hs[i] = h_hist[row + j];
        cts[i] = ctx_hist[row + j];
        cs2[i] = c_hist[row + j];
    }
    for (int i = tid; i < 16 * 128; i += 256) {
        const int bl = i >> 7, j = i & 127;
        xs[i] = x_hist[((size_t)t * BB + bq * 16 + bl) * EE + j];
    }
    __syncthreads();

    const int j = tid;
    float acc[16];
    #pragma unroll
    for (int bl = 0; bl < 16; ++bl) acc[bl] = 0.f;
    for (int r = 0; r < 256; ++r) {
        const float w0 = Wo[(size_t)r * HH + j];
        const float w1 = Wo[(size_t)(256 + r) * HH + j];
        #pragma unroll
        for (int bl = 0; bl < 16; ++bl)
            acc[bl] += hs[bl * 256 + r] * w0 + cts[bl * 256 + r] * w1;
    }
    #pragma unroll
    for (int bl = 0; bl < 16; ++bl)
        outs[((size_t)t * BB + bq * 16 + bl) * HH + j] = acc[bl] + bo[j];

    const int bl = tid >> 4, r16 = tid & 15;
    float p = 0.f;
    for (int i = r16; i < 256; i += 16)
        p += cts[bl * 256 + i] * Wp[i] + cs2[bl * 256 + i] * Wp[256 + i]
           + hs[bl * 256 + i] * Wp[512 + i];
    for (int i = r16; i < 128; i += 16)
        p += xs[bl * 128 + i] * Wp[768 + i];
    p += __shfl_xor(p, 1);
    p += __shfl_xor(p, 2);
    p += __shfl_xor(p, 4);
    p += __shfl_xor(p, 8);
    if (r16 == 0)
        pgens[(size_t)t * BB + bq * 16 + bl] = fsig(p + bp[0]);
}

extern "C" void kernel_launch(void* const* d_in, const int* in_sizes, int n_in,
                              void* d_out, int out_size, void* d_ws, size_t ws_size,
                              hipStream_t stream) {
    const float* dec_in = (const float*)d_in[0];
    const float* init_c = (const float*)d_in[1];
    const float* init_h = (const float*)d_in[2];
    const float* enc    = (const float*)d_in[3];
    const float* mask   = (const float*)d_in[4];
    const float* Wx = (const float*)d_in[5];
    const float* bx = (const float*)d_in[6];
    const float* Wl = (const float*)d_in[7];
    const float* bl = (const float*)d_in[8];
    const float* Ws = (const float*)d_in[9];
    const float* bs = (const float*)d_in[10];
    const float* v  = (const float*)d_in[11];
    const float* wc = (const float*)d_in[12];
    const float* Wp = (const float*)d_in[13];
    const float* bp = (const float*)d_in[14];
    const float* Wo = (const float*)d_in[15];
    const float* bo = (const float*)d_in[16];

    float* out   = (float*)d_out;
    float* outs  = out;                                   // T*B*H
    float* c_out = outs + (size_t)T_STEPS * BB * HH;      // B*H
    float* h_out = c_out + BB * HH;                       // B*H
    float* attns = h_out + BB * HH;                       // T*B*L
    float* pgens = attns + (size_t)T_STEPS * BB * LL;     // T*B
    float* cov   = pgens + T_STEPS * BB;                  // B*L

    float* ws     = (float*)d_ws;
    uint4* encb   = (uint4*)ws;                           // B*L*H bf16
    float* e_ws   = ws + (size_t)BB * LL * HH / 2;        // 2*B*L
    float* mp     = e_ws + 2 * BB * LL;                   // 32*B
    float* sp     = mp + NCHUNK * BB;                     // 32*B
    float* ctxp   = sp + NCHUNK * BB;                     // 32*B*H
    float* x_hist = ctxp + (size_t)NCHUNK * BB * HH;      // T*B*E
    float* df_ws  = x_hist + (size_t)T_STEPS * BB * EE;   // B*H
    float* m_ws   = df_ws + BB * HH;                      // B
    float* is_ws  = m_ws + BB;                            // B
    float* ctx_hist = is_ws + BB;                         // T*B*H
    float* c_hist = ctx_hist + (size_t)T_STEPS * BB * HH; // T*B*H
    float* h_hist = c_hist + (size_t)T_STEPS * BB * HH;   // T*B*H

    conv_kernel<<<4096, 256, 0, stream>>>((const float4*)enc, encb);

    for (int t = 0; t < T_STEPS; ++t) {
        recur_kernel<<<128, 256, 0, stream>>>(dec_in, mp, sp, ctxp,
            init_c, init_h, Wx, bx, Wl, bl,
            ctx_hist, x_hist, c_hist, h_hist, m_ws, is_ws, t);
        df_kernel<<<BB, 512, 0, stream>>>(c_hist, h_hist, Ws, bs, df_ws, t);
        attn_kernel<<<NCHUNK * BB, 256, 0, stream>>>(encb, mask, cov, df_ws,
            v, wc, e_ws, attns, m_ws, is_ws, mp, sp, ctxp, t);
    }
    recur_kernel<<<128, 256, 0, stream>>>(dec_in, mp, sp, ctxp,
        init_c, init_h, Wx, bx, Wl, bl,
        ctx_hist, x_hist, c_hist, h_hist, m_ws, is_ws, T_STEPS);
    epi_kernel<<<BB, 256, 0, stream>>>(e_ws, mask, m_ws, is_ws,
        c_hist, h_hist, attns, cov, c_out, h_out);
    out_kernel<<<256, 256, 0, stream>>>(h_hist, ctx_hist, c_hist, x_hist,
        Wo, bo, Wp, bp, outs, pgens);
}

// Round 7
// 4611.259 us; speedup vs baseline: 1.4573x; 1.4573x over previous
//
#include <hip/hip_runtime.h>
#include <math.h>

#define T_STEPS 64
#define BB 64
#define LL 2048
#define EE 128
#define HH 256
#define NCHUNK 32
#define LCHUNK (LL / NCHUNK) /* 64 */

__device__ __forceinline__ float fexp(float x) {
    return __builtin_amdgcn_exp2f(x * 1.44269504088896340736f);
}
__device__ __forceinline__ float fsig(float x) {
    return __builtin_amdgcn_rcpf(1.f + __builtin_amdgcn_exp2f(-1.44269504088896340736f * x));
}
__device__ __forceinline__ float ftanh(float x) {
    float xc = fminf(fmaxf(x, -20.f), 20.f);
    float p = __builtin_amdgcn_exp2f(2.885390081777926814f * xc); // e^{2x}
    return (p - 1.f) * __builtin_amdgcn_rcpf(p + 1.f);
}
__device__ __forceinline__ unsigned int bfr(float x) {
    unsigned int u = __float_as_uint(x);
    return (u + 0x7FFFu + ((u >> 16) & 1u)) >> 16;
}
__device__ __forceinline__ void bf8x(const uint4 q, float* f) {
    f[0] = __uint_as_float(q.x << 16); f[1] = __uint_as_float(q.x & 0xFFFF0000u);
    f[2] = __uint_as_float(q.y << 16); f[3] = __uint_as_float(q.y & 0xFFFF0000u);
    f[4] = __uint_as_float(q.z << 16); f[5] = __uint_as_float(q.z & 0xFFFF0000u);
    f[6] = __uint_as_float(q.w << 16); f[7] = __uint_as_float(q.w & 0xFFFF0000u);
}
__device__ __forceinline__ void load8(const float* p, float* d) {
    float4 a = *(const float4*)p, b = *(const float4*)(p + 4);
    d[0]=a.x; d[1]=a.y; d[2]=a.z; d[3]=a.w; d[4]=b.x; d[5]=b.y; d[6]=b.z; d[7]=b.w;
}

// ---------------------------------------------------------------------------
// K0: one-time fp32 -> bf16 conversion of enc (RNE).
// ---------------------------------------------------------------------------
__global__ __launch_bounds__(256) void conv_kernel(
    const float4* __restrict__ enc, uint4* __restrict__ encb)
{
    const int n = BB * LL * HH / 8;
    for (int i = blockIdx.x * 256 + threadIdx.x; i < n; i += gridDim.x * 256) {
        const float4 a = enc[2 * i], c = enc[2 * i + 1];
        uint4 o;
        o.x = bfr(a.x) | (bfr(a.y) << 16);
        o.y = bfr(a.z) | (bfr(a.w) << 16);
        o.z = bfr(c.x) | (bfr(c.y) << 16);
        o.w = bfr(c.z) | (bfr(c.w) << 16);
        encb[i] = o;
    }
}

// ---------------------------------------------------------------------------
// K1: attention pass for step t (bf16 enc), fused with step-(t-1) epilogue.
// NO online max: |e| <= sum|v_h| ~ 20, exp(e) <= 5e8, fp32-safe. Partials
// are plain sums -> short dependency chains, fewer registers.
// Wave = 4 row-subgroups x 16 h-chunks; depth-1 prefetch of next enc pair.
// Grid: NCHUNK*BB = 2048 blocks, 256 threads.
// ---------------------------------------------------------------------------
__global__ __launch_bounds__(256) void attn_kernel(
    const uint4* __restrict__ encb,  // (B*L, 32) uint4 (=256 bf16 per row)
    const float* __restrict__ mask,
    float* __restrict__ cov,
    const float* __restrict__ df,
    const float* __restrict__ v,
    const float* __restrict__ wc,
    float* __restrict__ e_ws,        // (2,B,L)
    float* __restrict__ attns,
    const float* __restrict__ is_ws, // (B) prev-step 1/S
    float* __restrict__ sp, float* __restrict__ ctxp,
    int t)
{
    const int prev_t = t - 1;
    const int g = blockIdx.x;
    const int b = g & (BB - 1);
    const int chunk = g >> 6;
    const int tid = threadIdx.x;
    const int wave = tid >> 6;
    const int lane = tid & 63;
    const int hc = lane & 15;
    const int lsub = lane >> 4;
    const int l0 = chunk * LCHUNK + wave * (LCHUNK / 4);

    const float* e_prev = e_ws + (size_t)(prev_t & 1) * BB * LL;
    float* e_cur = e_ws + (size_t)(t & 1) * BB * LL;
    const float iSprev = (prev_t >= 0) ? is_ws[b] : 0.f;

    // per-row scalars for all 4 rows (cheap, issued early)
    float mskv[4], covv[4], epv[4];
    #pragma unroll
    for (int mi = 0; mi < 4; ++mi) {
        const int idx = b * LL + l0 + mi * 4 + lsub;
        mskv[mi] = mask[idx];
        covv[mi] = (prev_t >= 0) ? cov[idx] : 0.f;
        epv[mi]  = (prev_t >= 0) ? e_prev[idx] : 0.f;
    }

    float dfv[16], vv[16], wcv[16];
    #pragma unroll
    for (int k = 0; k < 2; ++k) {
        load8(df + b * HH + hc * 8 + 128 * k, dfv + 8 * k);
        load8(v + hc * 8 + 128 * k, vv + 8 * k);
        load8(wc + hc * 8 + 128 * k, wcv + 8 * k);
    }

    // step-(t-1) epilogue: attn weight, coverage rmw
    float cvv[4];
    #pragma unroll
    for (int mi = 0; mi < 4; ++mi) {
        const int l = l0 + mi * 4 + lsub;
        const int idx = b * LL + l;
        if (prev_t >= 0) {
            const float a = fexp(epv[mi]) * mskv[mi] * iSprev;
            cvv[mi] = covv[mi] + a;
            if (hc == 0) {
                cov[idx] = cvv[mi];
                attns[((size_t)prev_t * BB + b) * LL + l] = a;
            }
        } else {
            cvv[mi] = 0.f;
            if (hc == 0) cov[idx] = 0.f;
        }
    }

    const uint4* ep0 = encb + (size_t)(b * LL + l0 + lsub) * 32 + hc;

    float s = 0.f;
    float cacc[16];
    #pragma unroll
    for (int j = 0; j < 16; ++j) cacc[j] = 0.f;

    uint4 eA0 = ep0[0], eA1 = ep0[16];

    #pragma unroll
    for (int mi = 0; mi < 4; ++mi) {
        uint4 eB0 = {0,0,0,0}, eB1 = {0,0,0,0};
        if (mi < 3) { eB0 = ep0[(mi + 1) * 128]; eB1 = ep0[(mi + 1) * 128 + 16]; }

        float fe[16];
        bf8x(eA0, fe); bf8x(eA1, fe + 8);
        float p = 0.f;
        #pragma unroll
        for (int j = 0; j < 16; ++j)
            p += vv[j] * ftanh(fe[j] + dfv[j] + cvv[mi] * wcv[j]);
        p += __shfl_xor(p, 1);
        p += __shfl_xor(p, 2);
        p += __shfl_xor(p, 4);
        p += __shfl_xor(p, 8);
        const int l = l0 + mi * 4 + lsub;
        if (hc == 0) e_cur[b * LL + l] = p;

        const float w = fexp(p) * mskv[mi];   // no max shift (bounded e)
        s += w;
        #pragma unroll
        for (int j = 0; j < 16; ++j) cacc[j] += w * fe[j];
        eA0 = eB0; eA1 = eB1;
    }

    // cross-subgroup butterfly: plain sums
    #pragma unroll
    for (int off = 16; off <= 32; off <<= 1) {
        s += __shfl_xor(s, off);
        #pragma unroll
        for (int j = 0; j < 16; ++j) cacc[j] += __shfl_xor(cacc[j], off);
    }

    __shared__ float lsum[4];
    __shared__ float lctx[4][HH];
    if (lsub == 0) {
        #pragma unroll
        for (int k = 0; k < 2; ++k)
            #pragma unroll
            for (int j = 0; j < 8; ++j)
                lctx[wave][hc * 8 + 128 * k + j] = cacc[k * 8 + j];
    }
    if (lane == 0) lsum[wave] = s;
    __syncthreads();

    const int pidx = chunk * BB + b;
    ctxp[(size_t)pidx * HH + tid] =
        lctx[0][tid] + lctx[1][tid] + lctx[2][tid] + lctx[3][tid];
    if (tid == 0)
        sp[pidx] = lsum[0] + lsum[1] + lsum[2] + lsum[3];
}

// ---------------------------------------------------------------------------
// K2: combine step-(t-1) partials -> ctx_{t-1} (plain sums), then
// x_t = relu([inp_t, ctx_{t-1}] @ W_x + b_x). Grid BB, 256 threads.
// ---------------------------------------------------------------------------
__global__ __launch_bounds__(256) void ctx_x_kernel(
    const float* __restrict__ dec_in,
    const float* __restrict__ sp, const float* __restrict__ ctxp,
    const float* __restrict__ Wx, const float* __restrict__ bx,
    float* __restrict__ ctx_hist, float* __restrict__ x_hist,
    float* __restrict__ is_ws, int t)
{
    const int b = blockIdx.x;
    const int tid = threadIdx.x;
    __shared__ float sctx[HH], siv[EE], xred[EE];

    if (t > 0) {
        float S = 0.f, cs = 0.f;
        #pragma unroll
        for (int k = 0; k < NCHUNK; ++k) {
            S += sp[k * BB + b];
            cs += ctxp[(size_t)(k * BB + b) * HH + tid];
        }
        const float invS = 1.f / S;
        const float cx = cs * invS;
        sctx[tid] = cx;
        ctx_hist[((size_t)(t - 1) * BB + b) * HH + tid] = cx;
        if (tid == 0) is_ws[b] = invS;
    } else {
        sctx[tid] = 0.f;
    }
    if (t < T_STEPS && tid < EE)
        siv[tid] = dec_in[((size_t)t * BB + b) * EE + tid];
    __syncthreads();

    if (t < T_STEPS) {
        const int j = tid & 127, q = tid >> 7;
        float a = 0.f;
        #pragma unroll 4
        for (int r = q * 192; r < q * 192 + 192; ++r) {
            const float f = (r < EE) ? siv[r] : sctx[r - EE];
            a += f * Wx[(size_t)r * EE + j];
        }
        if (q) xred[j] = a;
        __syncthreads();
        if (!q)
            x_hist[((size_t)t * BB + b) * EE + j] = fmaxf(a + xred[j] + bx[j], 0.f);
    }
}

// ---------------------------------------------------------------------------
// K3: LSTM z-GEMM + (c,h) update for step t. Grid 512 blocks = (unit u,
// batch-half), 128 threads = 4 gates x 32 batches.
// ---------------------------------------------------------------------------
__global__ __launch_bounds__(128) void lstm_kernel(
    const float* __restrict__ x_hist,
    const float* __restrict__ init_c, const float* __restrict__ init_h,
    const float* __restrict__ Wl, const float* __restrict__ bl,
    float* __restrict__ c_hist, float* __restrict__ h_hist, int t)
{
    const int u = blockIdx.x >> 1;
    const int half = blockIdx.x & 1;
    const int tid = threadIdx.x;
    __shared__ float f[32 * 385];
    __shared__ float wl[4 * 385];
    __shared__ float zs[4 * 32];

    const float* hsrc = (t == 0) ? init_h : (h_hist + (size_t)(t - 1) * BB * HH);
    const float* csrc = (t == 0) ? init_c : (c_hist + (size_t)(t - 1) * BB * HH);

    for (int i = tid; i < 32 * 128; i += 128) {
        const int mm = i >> 7, k = i & 127;
        f[mm * 385 + k] = x_hist[((size_t)t * BB + half * 32 + mm) * EE + k];
    }
    for (int i = tid; i < 32 * 256; i += 128) {
        const int mm = i >> 8, k = i & 255;
        f[mm * 385 + 128 + k] = hsrc[(half * 32 + mm) * HH + k];
    }
    for (int i = tid; i < 4 * 384; i += 128) {
        const int gg = i / 384, k = i - gg * 384;
        wl[gg * 385 + k] = Wl[(size_t)k * 1024 + gg * 256 + u];
    }
    __syncthreads();

    const int mm = tid & 31, gg = tid >> 5;
    float acc = bl[gg * 256 + u];
    const float* fr = f + mm * 385;
    const float* wr = wl + gg * 385;
    #pragma unroll 8
    for (int k = 0; k < 384; ++k) acc += fr[k] * wr[k];
    zs[gg * 32 + mm] = acc;
    __syncthreads();

    if (tid < 32) {
        const int mg = half * 32 + tid;
        const float zi = zs[tid], zf = zs[32 + tid], zg = zs[64 + tid], zo = zs[96 + tid];
        const float cp = csrc[mg * HH + u];
        const float cn = fsig(zf) * cp + fsig(zi) * ftanh(zg);
        const float hn = fsig(zo) * ftanh(cn);
        c_hist[((size_t)t * BB + mg) * HH + u] = cn;
        h_hist[((size_t)t * BB + mg) * HH + u] = hn;
    }
}

// ---------------------------------------------------------------------------
// K4: dec_feat_t = tanh([c_t, h_t] @ W_s + b_s). Grid BB, 512 threads.
// ---------------------------------------------------------------------------
__global__ __launch_bounds__(512) void df_kernel(
    const float* __restrict__ c_hist, const float* __restrict__ h_hist,
    const float* __restrict__ Ws, const float* __restrict__ bs,
    float* __restrict__ df_ws, int t)
{
    const int b = blockIdx.x;
    const int tid = threadIdx.x;
    __shared__ float sf[512];
    __shared__ float rbuf[256];
    sf[tid] = (tid < 256) ? c_hist[((size_t)t * BB + b) * HH + tid]
                          : h_hist[((size_t)t * BB + b) * HH + tid - 256];
    __syncthreads();
    const int j = tid & 255, half = tid >> 8;
    float a = 0.f;
    const float* wcol = Ws + (size_t)(half * 256) * HH + j;
    const float* src = sf + half * 256;
    #pragma unroll 4
    for (int r = 0; r < 256; ++r) a += src[r] * wcol[(size_t)r * HH];
    if (half) rbuf[j] = a;
    __syncthreads();
    if (!half) df_ws[b * HH + j] = ftanh(a + rbuf[j] + bs[j]);
}

// ---------------------------------------------------------------------------
// K5: epilogue: attns[T-1], final cov, c/h outputs. Grid BB, 256 threads.
// ---------------------------------------------------------------------------
__global__ __launch_bounds__(256) void epi_kernel(
    const float* __restrict__ e_ws, const float* __restrict__ mask,
    const float* __restrict__ is_ws,
    const float* __restrict__ c_hist, const float* __restrict__ h_hist,
    float* __restrict__ attns, float* __restrict__ cov,
    float* __restrict__ c_out, float* __restrict__ h_out)
{
    const int b = blockIdx.x;
    const int j = threadIdx.x;
    const float iS = is_ws[b];
    const float* e_last = e_ws + (size_t)((T_STEPS - 1) & 1) * BB * LL;
    for (int i = 0; i < LL / 256; ++i) {
        const int l = i * 256 + j;
        const int idx = b * LL + l;
        const float a = fexp(e_last[idx]) * mask[idx] * iS;
        attns[((size_t)(T_STEPS - 1) * BB + b) * LL + l] = a;
        cov[idx] += a;
    }
    c_out[b * HH + j] = c_hist[((size_t)(T_STEPS - 1) * BB + b) * HH + j];
    h_out[b * HH + j] = h_hist[((size_t)(T_STEPS - 1) * BB + b) * HH + j];
}

// ---------------------------------------------------------------------------
// K6: batched outs + pgens. Grid 256 blocks = (t, b-quarter), 512 threads.
// Split-K across thread-halves + unroll-4 -> 8 Wo loads in flight.
// ---------------------------------------------------------------------------
__global__ __launch_bounds__(512) void out_kernel(
    const float* __restrict__ h_hist, const float* __restrict__ ctx_hist,
    const float* __restrict__ c_hist, const float* __restrict__ x_hist,
    const float* __restrict__ Wo, const float* __restrict__ bo,
    const float* __restrict__ Wp, const float* __restrict__ bp,
    float* __restrict__ outs, float* __restrict__ pgens)
{
    const int t = blockIdx.x >> 2;
    const int bq = blockIdx.x & 3;
    const int tid = threadIdx.x;
    __shared__ float hs[16 * 256], cts[16 * 256], cs2[16 * 256], xs[16 * 128];
    __shared__ float zbuf[16 * 256];

    for (int i = tid; i < 16 * 256; i += 512) {
        const int bl = i >> 8, j = i & 255;
        const size_t row = ((size_t)t * BB + bq * 16 + bl) * HH;
        hs[i] = h_hist[row + j];
        cts[i] = ctx_hist[row + j];
        cs2[i] = c_hist[row + j];
    }
    for (int i = tid; i < 16 * 128; i += 512) {
        const int bl = i >> 7, j = i & 127;
        xs[i] = x_hist[((size_t)t * BB + bq * 16 + bl) * EE + j];
    }
    __syncthreads();

    // outs GEMM: j = tid&255, rh = tid>>8 covers r in [rh*128, rh*128+128)
    {
        const int j = tid & 255, rh = tid >> 8;
        float acc[16];
        #pragma unroll
        for (int bl = 0; bl < 16; ++bl) acc[bl] = 0.f;
        const int r0 = rh * 128;
        #pragma unroll 4
        for (int r = r0; r < r0 + 128; ++r) {
            const float w0 = Wo[(size_t)r * HH + j];
            const float w1 = Wo[(size_t)(256 + r) * HH + j];
            #pragma unroll
            for (int bl = 0; bl < 16; ++bl)
                acc[bl] += hs[bl * 256 + r] * w0 + cts[bl * 256 + r] * w1;
        }
        if (rh) {
            #pragma unroll
            for (int bl = 0; bl < 16; ++bl) zbuf[bl * 256 + j] = acc[bl];
        }
        __syncthreads();
        if (!rh) {
            #pragma unroll
            for (int bl = 0; bl < 16; ++bl)
                outs[((size_t)t * BB + bq * 16 + bl) * HH + j] =
                    acc[bl] + zbuf[bl * 256 + j] + bo[j];
        }
    }

    // pgens: 32 threads per batch row
    {
        const int bl = tid >> 5, r32 = tid & 31;
        float p = 0.f;
        for (int i = r32; i < 256; i += 32)
            p += cts[bl * 256 + i] * Wp[i] + cs2[bl * 256 + i] * Wp[256 + i]
               + hs[bl * 256 + i] * Wp[512 + i];
        for (int i = r32; i < 128; i += 32)
            p += xs[bl * 128 + i] * Wp[768 + i];
        p += __shfl_xor(p, 1);
        p += __shfl_xor(p, 2);
        p += __shfl_xor(p, 4);
        p += __shfl_xor(p, 8);
        p += __shfl_xor(p, 16);
        if (r32 == 0)
            pgens[(size_t)t * BB + bq * 16 + bl] = fsig(p + bp[0]);
    }
}

extern "C" void kernel_launch(void* const* d_in, const int* in_sizes, int n_in,
                              void* d_out, int out_size, void* d_ws, size_t ws_size,
                              hipStream_t stream) {
    const float* dec_in = (const float*)d_in[0];
    const float* init_c = (const float*)d_in[1];
    const float* init_h = (const float*)d_in[2];
    const float* enc    = (const float*)d_in[3];
    const float* mask   = (const float*)d_in[4];
    const float* Wx = (const float*)d_in[5];
    const float* bx = (const float*)d_in[6];
    const float* Wl = (const float*)d_in[7];
    const float* bl = (const float*)d_in[8];
    const float* Ws = (const float*)d_in[9];
    const float* bs = (const float*)d_in[10];
    const float* v  = (const float*)d_in[11];
    const float* wc = (const float*)d_in[12];
    const float* Wp = (const float*)d_in[13];
    const float* bp = (const float*)d_in[14];
    const float* Wo = (const float*)d_in[15];
    const float* bo = (const float*)d_in[16];

    float* out   = (float*)d_out;
    float* outs  = out;                                   // T*B*H
    float* c_out = outs + (size_t)T_STEPS * BB * HH;      // B*H
    float* h_out = c_out + BB * HH;                       // B*H
    float* attns = h_out + BB * HH;                       // T*B*L
    float* pgens = attns + (size_t)T_STEPS * BB * LL;     // T*B
    float* cov   = pgens + T_STEPS * BB;                  // B*L

    float* ws     = (float*)d_ws;
    uint4* encb   = (uint4*)ws;                           // B*L*H bf16
    float* e_ws   = ws + (size_t)BB * LL * HH / 2;        // 2*B*L
    float* sp     = e_ws + 2 * BB * LL;                   // 32*B
    float* ctxp   = sp + NCHUNK * BB;                     // 32*B*H
    float* x_hist = ctxp + (size_t)NCHUNK * BB * HH;      // T*B*E
    float* df_ws  = x_hist + (size_t)T_STEPS * BB * EE;   // B*H
    float* is_ws  = df_ws + BB * HH;                      // B
    float* ctx_hist = is_ws + BB;                         // T*B*H
    float* c_hist = ctx_hist + (size_t)T_STEPS * BB * HH; // T*B*H
    float* h_hist = c_hist + (size_t)T_STEPS * BB * HH;   // T*B*H

    conv_kernel<<<4096, 256, 0, stream>>>((const float4*)enc, encb);

    for (int t = 0; t < T_STEPS; ++t) {
        ctx_x_kernel<<<BB, 256, 0, stream>>>(dec_in, sp, ctxp, Wx, bx,
            ctx_hist, x_hist, is_ws, t);
        lstm_kernel<<<512, 128, 0, stream>>>(x_hist, init_c, init_h, Wl, bl,
            c_hist, h_hist, t);
        df_kernel<<<BB, 512, 0, stream>>>(c_hist, h_hist, Ws, bs, df_ws, t);
        attn_kernel<<<NCHUNK * BB, 256, 0, stream>>>(encb, mask, cov, df_ws,
            v, wc, e_ws, attns, is_ws, sp, ctxp, t);
    }
    ctx_x_kernel<<<BB, 256, 0, stream>>>(dec_in, sp, ctxp, Wx, bx,
        ctx_hist, x_hist, is_ws, T_STEPS);
    epi_kernel<<<BB, 256, 0, stream>>>(e_ws, mask, is_ws,
        c_hist, h_hist, attns, cov, c_out, h_out);
    out_kernel<<<256, 512, 0, stream>>>(h_hist, ctx_hist, c_hist, x_hist,
        Wo, bo, Wp, bp, outs, pgens);
}